// Round 8
// baseline (1449.040 us; speedup 1.0000x reference)
//
#include <hip/hip_runtime.h>

#define T_ 12
#define L_ 1024
#define H_ 64
#define HOR_ 12
#define BH_ 2048

typedef unsigned short u16;
typedef __attribute__((ext_vector_type(8))) __bf16 bf16x8;
typedef __attribute__((ext_vector_type(4))) float f32x4;

__device__ __forceinline__ u16 f2b(float f) {
  union { float f; unsigned u; } v; v.f = f;
  unsigned r = v.u + 0x7FFFu + ((v.u >> 16) & 1u);
  return (u16)(r >> 16);
}
__device__ __forceinline__ float b2f(u16 b) {
  union { unsigned u; float f; } v; v.u = ((unsigned)b) << 16;
  return v.f;
}
__device__ __forceinline__ void gld16(const void* g, void* l) {
  __builtin_amdgcn_global_load_lds((const __attribute__((address_space(1))) void*)g,
                                   (__attribute__((address_space(3))) void*)l, 16, 0, 0);
}

__global__ void k_zero(uint4* __restrict__ p, int n) {
  int i = blockIdx.x * blockDim.x + threadIdx.x;
  if (i < n) p[i] = make_uint4(0u, 0u, 0u, 0u);
}

// ---------------- fp32 -> bf16 convert (layout preserved) ----------------
__global__ void k_cvt(const float* __restrict__ in, u16* __restrict__ out, int n4) {
  int i = blockIdx.x * blockDim.x + threadIdx.x;
  if (i < n4) {
    float4 v = ((const float4*)in)[i];
    ushort4 o;
    o.x = f2b(v.x); o.y = f2b(v.y); o.z = f2b(v.z); o.w = f2b(v.w);
    ((ushort4*)out)[i] = o;
  }
}

// ------------- per-link 64x64 transpose: WT[l][k][h] = W[l][h][k] -------------
__global__ void k_tg(const float* __restrict__ W, u16* __restrict__ WT) {
  const int l = blockIdx.x;
  const float* w = W + (size_t)l * 4096;
  u16* t = WT + (size_t)l * 4096;
  for (int idx = threadIdx.x; idx < 4096; idx += blockDim.x) {
    int h = idx >> 6, k = idx & 63;
    t[k * 64 + h] = f2b(w[idx]);
  }
}

// -------- 128x128 bf16 NT GEMM: C[M,N] = A[M,K] * B[N,K]^T, fp32 acc --------
template <int OUT_BF16>
__global__ __launch_bounds__(256) void k_gemm128(const u16* __restrict__ A,
                                                 const u16* __restrict__ Bm,
                                                 void* __restrict__ C, int N, int K) {
  __shared__ __align__(16) u16 lA[128 * 32];
  __shared__ __align__(16) u16 lB[128 * 32];
  const int tid = threadIdx.x;
  const int lane = tid & 63, wv = tid >> 6;
  const int m0 = blockIdx.y * 128, n0 = blockIdx.x * 128;
  const int wm = (wv >> 1) * 64, wn = (wv & 1) * 64;
  const int r16 = lane & 15, q4 = lane >> 4;
  f32x4 acc[4][4] = {};
  for (int k0 = 0; k0 < K; k0 += 32) {
    __syncthreads();
#pragma unroll
    for (int j = 0; j < 2; ++j) {
      int ci = j * 256 + tid;          // 512 chunks of 16B per tile
      int row = ci >> 2, c = ci & 3;   // 128 rows x 4 chunks
      gld16(A + (size_t)(m0 + row) * K + k0 + c * 8, lA + ci * 8);
      gld16(Bm + (size_t)(n0 + row) * K + k0 + c * 8, lB + ci * 8);
    }
    __syncthreads();
    bf16x8 af[4], bfv[4];
#pragma unroll
    for (int u = 0; u < 4; ++u) {
      af[u]  = *(const bf16x8*)&lA[(wm + u * 16 + r16) * 32 + q4 * 8];
      bfv[u] = *(const bf16x8*)&lB[(wn + u * 16 + r16) * 32 + q4 * 8];
    }
#pragma unroll
    for (int i = 0; i < 4; ++i)
#pragma unroll
      for (int j = 0; j < 4; ++j)
        acc[i][j] = __builtin_amdgcn_mfma_f32_16x16x32_bf16(af[i], bfv[j], acc[i][j], 0, 0, 0);
  }
#pragma unroll
  for (int i = 0; i < 4; ++i)
#pragma unroll
    for (int j = 0; j < 4; ++j)
#pragma unroll
      for (int e = 0; e < 4; ++e) {
        size_t row = m0 + wm + i * 16 + q4 * 4 + e;
        size_t col = n0 + wn + j * 16 + r16;
        if (OUT_BF16) ((u16*)C)[row * N + col] = f2b(acc[i][j][e]);
        else          ((float*)C)[row * N + col] = acc[i][j][e];
      }
}

// -------- M=32 bf16 NT GEMM (decoder input-attn): C[32,N] fp32 --------
__global__ __launch_bounds__(256) void k_gemm32(const u16* __restrict__ A,
                                                const u16* __restrict__ Bm,
                                                float* __restrict__ C, int N, int K) {
  __shared__ __align__(16) u16 lA[32 * 32];
  __shared__ __align__(16) u16 lB[128 * 32];
  const int tid = threadIdx.x;
  const int lane = tid & 63, wv = tid >> 6;
  const int n0 = blockIdx.x * 128;
  const int r16 = lane & 15, q4 = lane >> 4;
  f32x4 acc[2][2] = {};
  for (int k0 = 0; k0 < K; k0 += 32) {
    __syncthreads();
    if (tid < 128) {
      int row = tid >> 2, c = tid & 3;
      gld16(A + (size_t)row * K + k0 + c * 8, lA + tid * 8);
    }
#pragma unroll
    for (int j = 0; j < 2; ++j) {
      int ci = j * 256 + tid;
      int row = ci >> 2, c = ci & 3;
      gld16(Bm + (size_t)(n0 + row) * K + k0 + c * 8, lB + ci * 8);
    }
    __syncthreads();
    bf16x8 af[2], bfv[2];
#pragma unroll
    for (int u = 0; u < 2; ++u) {
      af[u]  = *(const bf16x8*)&lA[(u * 16 + r16) * 32 + q4 * 8];
      bfv[u] = *(const bf16x8*)&lB[(wv * 32 + u * 16 + r16) * 32 + q4 * 8];
    }
#pragma unroll
    for (int i = 0; i < 2; ++i)
#pragma unroll
      for (int j = 0; j < 2; ++j)
        acc[i][j] = __builtin_amdgcn_mfma_f32_16x16x32_bf16(af[i], bfv[j], acc[i][j], 0, 0, 0);
  }
#pragma unroll
  for (int i = 0; i < 2; ++i)
#pragma unroll
    for (int j = 0; j < 2; ++j)
#pragma unroll
      for (int e = 0; e < 4; ++e)
        C[(size_t)(i * 16 + q4 * 4 + e) * N + n0 + wv * 32 + j * 16 + r16] = acc[i][j][e];
}

// -------- decoder fc: out_i[b,l] = sum_h H[b,h,l]*fcw[l,h] + fcb[l] --------
__global__ void k_fc(const u16* __restrict__ Hb, const float* __restrict__ fcw,
                     const float* __restrict__ fcb, float* __restrict__ outp,
                     u16* __restrict__ outfc, int s) {
  const int b = blockIdx.x >> 2;
  const int li = (blockIdx.x & 3) * 256 + threadIdx.x;
  float acc = fcb[li];
  const u16* hp = Hb + (size_t)b * H_ * L_ + li;
  const float* wp = fcw + (size_t)li * H_;
#pragma unroll 8
  for (int h = 0; h < H_; ++h) acc += b2f(hp[(size_t)h * L_]) * wp[h];
  outp[((size_t)b * HOR_ + s) * L_ + li] = acc;   // d_out[b][s][l] (FLOAT32)
  outfc[(size_t)b * L_ + li] = f2b(acc);          // feeds decoder input-attn GEMM
}

// -------- per-link gate GEMMs + pointwise GRU update --------
__device__ __forceinline__ void gate_mma(const u16* __restrict__ w, const bf16x8 (&a)[2][2],
                                         f32x4 (&acc)[2][4], int r16, int q4) {
#pragma unroll
  for (int nt = 0; nt < 4; ++nt)
#pragma unroll
    for (int kt = 0; kt < 2; ++kt) {
      bf16x8 bfr = *(const bf16x8*)&w[(nt * 16 + r16) * 64 + kt * 32 + q4 * 8];
#pragma unroll
      for (int mt = 0; mt < 2; ++mt)
        acc[mt][nt] = __builtin_amdgcn_mfma_f32_16x16x32_bf16(a[mt][kt], bfr, acc[mt][nt], 0, 0, 0);
    }
}

template <int ENC>
__global__ __launch_bounds__(512) void k_gates(
    const u16* __restrict__ Aalt, const u16* __restrict__ WTr, const u16* __restrict__ WTz,
    const u16* __restrict__ WTn, const float* __restrict__ brh, const float* __restrict__ bzh,
    const float* __restrict__ bnh, const float* __restrict__ Wir, const float* __restrict__ Wiz,
    const float* __restrict__ Win, const float* __restrict__ bri, const float* __restrict__ bzi,
    const float* __restrict__ bni, const float* __restrict__ inp, int t, u16* __restrict__ Hb) {
  __shared__ __align__(16) u16 lout[BH_ * 8];
  const int tid = threadIdx.x;
  const int lane = tid & 63, wv = tid >> 6;   // 8 waves, one link each
  const int l = blockIdx.x * 8 + wv;
  const int r16 = lane & 15, q4 = lane >> 4;
  const u16* al = Aalt + (size_t)l * BH_;     // A[l][b*64+h], bf16
  bf16x8 a[2][2];
#pragma unroll
  for (int mt = 0; mt < 2; ++mt)
#pragma unroll
    for (int kt = 0; kt < 2; ++kt)
      a[mt][kt] = *(const bf16x8*)&al[(mt * 16 + r16) * 64 + kt * 32 + q4 * 8];
  f32x4 aR[2][4] = {}, aZ[2][4] = {}, aN[2][4] = {};
  gate_mma(WTr + (size_t)l * 4096, a, aR, r16, q4);
  gate_mma(WTz + (size_t)l * 4096, a, aZ, r16, q4);
  gate_mma(WTn + (size_t)l * 4096, a, aN, r16, q4);

  float i0v[2][4], i1v[2][4];
#pragma unroll
  for (int mt = 0; mt < 2; ++mt)
#pragma unroll
    for (int e = 0; e < 4; ++e) {
      int bb = mt * 16 + q4 * 4 + e;
      if (ENC) {
        i0v[mt][e] = inp[(((size_t)bb * T_ + t) * 2 + 0) * L_ + l];
        i1v[mt][e] = inp[(((size_t)bb * T_ + t) * 2 + 1) * L_ + l];
      } else {
        i0v[mt][e] = inp[(size_t)bb * L_ + l];
        i1v[mt][e] = 0.f;
      }
    }
#pragma unroll
  for (int nt = 0; nt < 4; ++nt) {
    const int kk = nt * 16 + r16;
    const float vbrh = brh[kk * L_ + l], vbzh = bzh[kk * L_ + l], vbnh = bnh[kk * L_ + l];
    const float vbri = bri[kk * L_ + l], vbzi = bzi[kk * L_ + l], vbni = bni[kk * L_ + l];
    const float wr0 = Wir[l * 128 + kk], wr1 = Wir[l * 128 + 64 + kk];
    const float wz0 = Wiz[l * 128 + kk], wz1 = Wiz[l * 128 + 64 + kk];
    const float wn0 = Win[l * 128 + kk], wn1 = Win[l * 128 + 64 + kk];
#pragma unroll
    for (int mt = 0; mt < 2; ++mt)
#pragma unroll
      for (int e = 0; e < 4; ++e) {
        const int bb = mt * 16 + q4 * 4 + e;
        const float i0 = i0v[mt][e], i1 = i1v[mt][e];
        const float gr = aR[mt][nt][e] + vbrh + i0 * wr0 + i1 * wr1 + vbri;
        const float gz = aZ[mt][nt][e] + vbzh + i0 * wz0 + i1 * wz1 + vbzi;
        const float gnh = aN[mt][nt][e] + vbnh;          // r multiplies (Wn·A + bn_h)
        const float gni = i0 * wn0 + i1 * wn1 + vbni;
        const float rr = 1.f / (1.f + __expf(-gr));
        const float zz = 1.f / (1.f + __expf(-gz));
        const float xx = rr * gnh + gni;
        const float ex = __expf(2.f * xx);
        const float nn = (ex - 1.f) / (ex + 1.f);        // tanh
        const float av = b2f(al[bb * 64 + kk]);          // attn'd hidden
        const float hh = (1.f - zz) * nn + zz * av;
        lout[(bb * 64 + kk) * 8 + wv] = f2b(hh);
      }
  }
  __syncthreads();
  const int c0 = blockIdx.x * 8;                         // transpose-out: H[b*64+h][l]
  for (int i = tid; i < BH_; i += 512)
    *(uint4*)(Hb + (size_t)i * L_ + c0) = *(const uint4*)&lout[i * 8];
}

// ---------------- workspace map (bytes) ----------------
#define WS_H     (size_t)0          // bf16 H[b*64+h][l]        4 MB
#define WS_AALT  ((size_t)4 << 20)  // bf16 A[l][b*64+h]        4 MB
#define WS_WHB   ((size_t)8 << 20)  // bf16 Wh[m][l]            2 MB
#define WS_WIB   ((size_t)10 << 20) // bf16 Wi[m][l]            2 MB
#define WS_XB    ((size_t)12 << 20) // bf16 x rows (b,t,f)[l]   1.5 MB
#define WS_WTR   ((size_t)14 << 20) // bf16 WT_r[l][k][h]       8 MB
#define WS_WTZ   ((size_t)22 << 20)
#define WS_WTN   ((size_t)30 << 20)
#define WS_ENCIN ((size_t)38 << 20) // f32 ENCIN[(b,t,f)][m]    3 MB
#define WS_DECIN ((size_t)42 << 20) // f32 DECIN[b][m]          128 KB
#define WS_OUTFC ((size_t)43 << 20) // bf16 OUTFC[b][l]         64 KB

extern "C" void kernel_launch(void* const* d_in, const int* in_sizes, int n_in,
                              void* d_out, int out_size, void* d_ws, size_t ws_size,
                              hipStream_t stream) {
  const float* x   = (const float*)d_in[0];
  const float* Wi  = (const float*)d_in[1];
  const float* Wh  = (const float*)d_in[2];
  const float* Wrh = (const float*)d_in[3];
  const float* brh = (const float*)d_in[4];
  const float* Wri = (const float*)d_in[5];
  const float* bri = (const float*)d_in[6];
  const float* Wzh = (const float*)d_in[7];
  const float* bzh = (const float*)d_in[8];
  const float* Wzi = (const float*)d_in[9];
  const float* bzi = (const float*)d_in[10];
  const float* Wnh = (const float*)d_in[11];
  const float* bnh = (const float*)d_in[12];
  const float* Wni = (const float*)d_in[13];
  const float* bni = (const float*)d_in[14];
  const float* fcw = (const float*)d_in[15];
  const float* fcb = (const float*)d_in[16];
  float* out = (float*)d_out;                           // <-- FLOAT32 output

  char* ws = (char*)d_ws;
  u16*   Hb    = (u16*)(ws + WS_H);
  u16*   Aalt  = (u16*)(ws + WS_AALT);
  u16*   Whb   = (u16*)(ws + WS_WHB);
  u16*   Wib   = (u16*)(ws + WS_WIB);
  u16*   xb    = (u16*)(ws + WS_XB);
  u16*   WTr   = (u16*)(ws + WS_WTR);
  u16*   WTz   = (u16*)(ws + WS_WTZ);
  u16*   WTn   = (u16*)(ws + WS_WTN);
  float* ENCIN = (float*)(ws + WS_ENCIN);
  float* DECIN = (float*)(ws + WS_DECIN);
  u16*   OUTFC = (u16*)(ws + WS_OUTFC);

  k_zero<<<1024, 256, 0, stream>>>((uint4*)Hb, 262144);  // h0 = 0 (4 MB)
  k_cvt<<<1024, 256, 0, stream>>>(Wh, Whb, 262144);
  k_cvt<<<1024, 256, 0, stream>>>(Wi, Wib, 262144);
  k_cvt<<<768, 256, 0, stream>>>(x, xb, 196608);
  k_tg<<<1024, 256, 0, stream>>>(Wrh, WTr);
  k_tg<<<1024, 256, 0, stream>>>(Wzh, WTz);
  k_tg<<<1024, 256, 0, stream>>>(Wnh, WTn);
  // all-timestep encoder input attn: ENCIN[(b,t,f)][m] = sum_l x * Wi[m,l]
  k_gemm128<0><<<dim3(8, 6), 256, 0, stream>>>(xb, Wib, ENCIN, 1024, 1024);

  for (int t = 0; t < T_; ++t) {
    // Aalt[m][bh] = sum_l Wh[m,l] * H[bh,l]
    k_gemm128<1><<<dim3(16, 8), 256, 0, stream>>>(Whb, Hb, Aalt, 2048, 1024);
    k_gates<1><<<128, 512, 0, stream>>>(Aalt, WTr, WTz, WTn, brh, bzh, bnh,
                                        Wri, Wzi, Wni, bri, bzi, bni, ENCIN, t, Hb);
  }
  for (int s = 0; s < HOR_; ++s) {
    k_fc<<<128, 256, 0, stream>>>(Hb, fcw, fcb, out, OUTFC, s);
    k_gemm32<<<8, 256, 0, stream>>>(OUTFC, Wib, DECIN, 1024, 1024);
    k_gemm128<1><<<dim3(16, 8), 256, 0, stream>>>(Whb, Hb, Aalt, 2048, 1024);
    k_gates<0><<<128, 512, 0, stream>>>(Aalt, WTr, WTz, WTn, brh, bzh, bnh,
                                        Wri, Wzi, Wni, bri, bzi, bni, DECIN, 0, Hb);
  }
}

// Round 9
// 1078.674 us; speedup vs baseline: 1.3434x; 1.3434x over previous
//
#include <hip/hip_runtime.h>

#define T_ 12
#define L_ 1024
#define H_ 64
#define HOR_ 12
#define BH_ 2048

typedef unsigned short u16;
typedef __attribute__((ext_vector_type(8))) __bf16 bf16x8;
typedef __attribute__((ext_vector_type(4))) float f32x4;

__device__ __forceinline__ u16 f2b(float f) {
  union { float f; unsigned u; } v; v.f = f;
  unsigned r = v.u + 0x7FFFu + ((v.u >> 16) & 1u);
  return (u16)(r >> 16);
}
__device__ __forceinline__ float b2f(u16 b) {
  union { unsigned u; float f; } v; v.u = ((unsigned)b) << 16;
  return v.f;
}
__device__ __forceinline__ void gld16(const void* g, void* l) {
  __builtin_amdgcn_global_load_lds((const __attribute__((address_space(1))) void*)g,
                                   (__attribute__((address_space(3))) void*)l, 16, 0, 0);
}

__global__ void k_zero(uint4* __restrict__ p, int n) {
  int i = blockIdx.x * blockDim.x + threadIdx.x;
  if (i < n) p[i] = make_uint4(0u, 0u, 0u, 0u);
}

// ---------------- fp32 -> bf16 convert (layout preserved) ----------------
__global__ void k_cvt(const float* __restrict__ in, u16* __restrict__ out, int n4) {
  int i = blockIdx.x * blockDim.x + threadIdx.x;
  if (i < n4) {
    float4 v = ((const float4*)in)[i];
    ushort4 o;
    o.x = f2b(v.x); o.y = f2b(v.y); o.z = f2b(v.z); o.w = f2b(v.w);
    ((ushort4*)out)[i] = o;
  }
}

// ------------- per-link 64x64 transpose: WT[l][k][h] = W[l][h][k] -------------
__global__ void k_tg(const float* __restrict__ W, u16* __restrict__ WT) {
  const int l = blockIdx.x;
  const float* w = W + (size_t)l * 4096;
  u16* t = WT + (size_t)l * 4096;
  for (int idx = threadIdx.x; idx < 4096; idx += blockDim.x) {
    int h = idx >> 6, k = idx & 63;
    t[k * 64 + h] = f2b(w[idx]);
  }
}

// ---- bias pre-transpose+combine: [k][l] scattered -> [l][k] coalesced ----
__global__ __launch_bounds__(64) void k_bias(
    const float* __restrict__ brh, const float* __restrict__ bri,
    const float* __restrict__ bzh, const float* __restrict__ bzi,
    const float* __restrict__ bnh, const float* __restrict__ bni,
    float* __restrict__ BRZ, float* __restrict__ BZZ,
    float* __restrict__ BNH, float* __restrict__ BNI) {
  const int l = blockIdx.x, k = threadIdx.x;
  const int i = k * 1024 + l, o = l * 64 + k;
  BRZ[o] = brh[i] + bri[i];
  BZZ[o] = bzh[i] + bzi[i];
  BNH[o] = bnh[i];
  BNI[o] = bni[i];
}

// -------- 64x128 bf16 NT GEMM: C[M,N] = A[M,K] * B[N,K]^T, fp32 acc --------
template <int OUT_BF16>
__global__ __launch_bounds__(256) void k_gemm128(const u16* __restrict__ A,
                                                 const u16* __restrict__ Bm,
                                                 void* __restrict__ C, int N, int K) {
  __shared__ __align__(16) u16 lA[64 * 32];
  __shared__ __align__(16) u16 lB[128 * 32];
  const int tid = threadIdx.x;
  const int lane = tid & 63, wv = tid >> 6;
  const int m0 = blockIdx.y * 64, n0 = blockIdx.x * 128;
  const int wm = (wv >> 1) * 32, wn = (wv & 1) * 64;
  const int r16 = lane & 15, q4 = lane >> 4;
  f32x4 acc[2][4] = {};
  for (int k0 = 0; k0 < K; k0 += 32) {
    __syncthreads();
    {
      int row = tid >> 2, c = tid & 3;    // 64 rows x 4 chunks of 16B
      gld16(A + (size_t)(m0 + row) * K + k0 + c * 8, lA + tid * 8);
    }
#pragma unroll
    for (int j = 0; j < 2; ++j) {
      int ci = j * 256 + tid;             // 128 rows x 4 chunks
      int row = ci >> 2, c = ci & 3;
      gld16(Bm + (size_t)(n0 + row) * K + k0 + c * 8, lB + ci * 8);
    }
    __syncthreads();
    bf16x8 af[2], bfv[4];
#pragma unroll
    for (int u = 0; u < 2; ++u)
      af[u] = *(const bf16x8*)&lA[(wm + u * 16 + r16) * 32 + q4 * 8];
#pragma unroll
    for (int u = 0; u < 4; ++u)
      bfv[u] = *(const bf16x8*)&lB[(wn + u * 16 + r16) * 32 + q4 * 8];
#pragma unroll
    for (int i = 0; i < 2; ++i)
#pragma unroll
      for (int j = 0; j < 4; ++j)
        acc[i][j] = __builtin_amdgcn_mfma_f32_16x16x32_bf16(af[i], bfv[j], acc[i][j], 0, 0, 0);
  }
#pragma unroll
  for (int i = 0; i < 2; ++i)
#pragma unroll
    for (int j = 0; j < 4; ++j)
#pragma unroll
      for (int e = 0; e < 4; ++e) {
        size_t row = m0 + wm + i * 16 + q4 * 4 + e;
        size_t col = n0 + wn + j * 16 + r16;
        if (OUT_BF16) ((u16*)C)[row * N + col] = f2b(acc[i][j][e]);
        else          ((float*)C)[row * N + col] = acc[i][j][e];
      }
}

// -------- M=32 split-K GEMM (decoder input-attn): PK[kq][32][1024] fp32 --------
__global__ __launch_bounds__(256) void k_gemm32(const u16* __restrict__ A,
                                                const u16* __restrict__ Bm,
                                                float* __restrict__ PK) {
  __shared__ __align__(16) u16 lA[32 * 32];
  __shared__ __align__(16) u16 lB[128 * 32];
  const int tid = threadIdx.x;
  const int lane = tid & 63, wv = tid >> 6;
  const int n0 = blockIdx.x * 128;
  const int kq = blockIdx.y;
  const int r16 = lane & 15, q4 = lane >> 4;
  f32x4 acc[2][2] = {};
  for (int k0 = kq * 256; k0 < kq * 256 + 256; k0 += 32) {
    __syncthreads();
    if (tid < 128) {
      int row = tid >> 2, c = tid & 3;
      gld16(A + (size_t)row * 1024 + k0 + c * 8, lA + tid * 8);
    }
#pragma unroll
    for (int j = 0; j < 2; ++j) {
      int ci = j * 256 + tid;
      int row = ci >> 2, c = ci & 3;
      gld16(Bm + (size_t)(n0 + row) * 1024 + k0 + c * 8, lB + ci * 8);
    }
    __syncthreads();
    bf16x8 af[2], bfv[2];
#pragma unroll
    for (int u = 0; u < 2; ++u) {
      af[u]  = *(const bf16x8*)&lA[(u * 16 + r16) * 32 + q4 * 8];
      bfv[u] = *(const bf16x8*)&lB[(wv * 32 + u * 16 + r16) * 32 + q4 * 8];
    }
#pragma unroll
    for (int i = 0; i < 2; ++i)
#pragma unroll
      for (int j = 0; j < 2; ++j)
        acc[i][j] = __builtin_amdgcn_mfma_f32_16x16x32_bf16(af[i], bfv[j], acc[i][j], 0, 0, 0);
  }
  float* C = PK + (size_t)kq * 32768;
#pragma unroll
  for (int i = 0; i < 2; ++i)
#pragma unroll
    for (int j = 0; j < 2; ++j)
#pragma unroll
      for (int e = 0; e < 4; ++e)
        C[(size_t)(i * 16 + q4 * 4 + e) * 1024 + n0 + wv * 32 + j * 16 + r16] = acc[i][j][e];
}

// -------- decoder fc (split-h): out[b,s,l] f32 + bf16 feedback --------
__global__ __launch_bounds__(256) void k_fc(const u16* __restrict__ Hb,
                                            const float* __restrict__ fcw,
                                            const float* __restrict__ fcb,
                                            float* __restrict__ outp,
                                            u16* __restrict__ outfc, int s) {
  __shared__ float part[256];
  const int b = blockIdx.x >> 3;
  const int li0 = (blockIdx.x & 7) * 128;
  const int half = threadIdx.x >> 7;
  const int lt = threadIdx.x & 127;
  const int li = li0 + lt;
  float acc = 0.f;
  const u16* hp = Hb + (size_t)b * 65536 + (size_t)(half * 32) * 1024 + li;
  const float* wp = fcw + (size_t)li * 64 + half * 32;
#pragma unroll 8
  for (int h = 0; h < 32; ++h) acc += b2f(hp[(size_t)h * 1024]) * wp[h];
  part[threadIdx.x] = acc;
  __syncthreads();
  if (threadIdx.x < 128) {
    float v = part[threadIdx.x] + part[threadIdx.x + 128] + fcb[li0 + threadIdx.x];
    outp[((size_t)b * HOR_ + s) * L_ + li0 + threadIdx.x] = v;
    outfc[(size_t)b * L_ + li0 + threadIdx.x] = f2b(v);
  }
}

// -------- gates: 4 waves/link (M-half x N-half), 2 links/block --------
template <int ENC>
__global__ __launch_bounds__(512, 4) void k_gates(
    const u16* __restrict__ Aalt, const u16* __restrict__ WTr, const u16* __restrict__ WTz,
    const u16* __restrict__ WTn, const float* __restrict__ BRZ, const float* __restrict__ BZZ,
    const float* __restrict__ BNH, const float* __restrict__ BNI,
    const float* __restrict__ Wir, const float* __restrict__ Wiz, const float* __restrict__ Win,
    const float* __restrict__ inp, int t, u16* __restrict__ Hb) {
  __shared__ __align__(8) u16 lout[BH_ * 2];
  const int tid = threadIdx.x;
  const int lane = tid & 63, wv = tid >> 6;
  const int li = wv >> 2, mh = (wv >> 1) & 1, nh = wv & 1;
  const int bid = blockIdx.x;
  const int wg = (bid & 7) * 64 + (bid >> 3);   // chunked XCD map: XCD x -> links [x*128,(x+1)*128)
  const int l = wg * 2 + li;
  const int r16 = lane & 15, q4 = lane >> 4;
  const u16* al = Aalt + (size_t)l * BH_;
  bf16x8 a[2];
#pragma unroll
  for (int kt = 0; kt < 2; ++kt)
    a[kt] = *(const bf16x8*)&al[(mh * 16 + r16) * 64 + kt * 32 + q4 * 8];
  f32x4 aR[2] = {}, aZ[2] = {}, aN[2] = {};
  const size_t wbase = (size_t)l * 4096 + (size_t)(nh * 32 + r16) * 64 + q4 * 8;
#define DO_GATE(W, acc)                                                              \
  {                                                                                  \
    bf16x8 w00 = *(const bf16x8*)&W[wbase];                                          \
    bf16x8 w01 = *(const bf16x8*)&W[wbase + 32];                                     \
    bf16x8 w10 = *(const bf16x8*)&W[wbase + 1024];                                   \
    bf16x8 w11 = *(const bf16x8*)&W[wbase + 1024 + 32];                              \
    acc[0] = __builtin_amdgcn_mfma_f32_16x16x32_bf16(a[0], w00, acc[0], 0, 0, 0);    \
    acc[0] = __builtin_amdgcn_mfma_f32_16x16x32_bf16(a[1], w01, acc[0], 0, 0, 0);    \
    acc[1] = __builtin_amdgcn_mfma_f32_16x16x32_bf16(a[0], w10, acc[1], 0, 0, 0);    \
    acc[1] = __builtin_amdgcn_mfma_f32_16x16x32_bf16(a[1], w11, acc[1], 0, 0, 0);    \
  }
  DO_GATE(WTr, aR)
  DO_GATE(WTz, aZ)
  DO_GATE(WTn, aN)
#undef DO_GATE

  float i0v[4], i1v[4];
#pragma unroll
  for (int e = 0; e < 4; ++e) {
    const int bb = mh * 16 + q4 * 4 + e;
    if (ENC) {
      i0v[e] = inp[(((size_t)bb * T_ + t) * 2 + 0) * L_ + l];
      i1v[e] = inp[(((size_t)bb * T_ + t) * 2 + 1) * L_ + l];
    } else {
      float sum = 0.f;
#pragma unroll
      for (int kq = 0; kq < 4; ++kq) sum += inp[kq * 32768 + (size_t)bb * L_ + l];
      i0v[e] = sum; i1v[e] = 0.f;
    }
  }
#pragma unroll
  for (int ntl = 0; ntl < 2; ++ntl) {
    const int kk = nh * 32 + ntl * 16 + r16;
    const float vbr = BRZ[l * 64 + kk];
    const float vbz = BZZ[l * 64 + kk];
    const float vbnh = BNH[l * 64 + kk];
    const float vbni = BNI[l * 64 + kk];
    const float wr0 = Wir[l * 128 + kk], wr1 = Wir[l * 128 + 64 + kk];
    const float wz0 = Wiz[l * 128 + kk], wz1 = Wiz[l * 128 + 64 + kk];
    const float wn0 = Win[l * 128 + kk], wn1 = Win[l * 128 + 64 + kk];
#pragma unroll
    for (int e = 0; e < 4; ++e) {
      const int bb = mh * 16 + q4 * 4 + e;
      const float i0 = i0v[e], i1 = i1v[e];
      const float gr = aR[ntl][e] + vbr + i0 * wr0 + i1 * wr1;
      const float gz = aZ[ntl][e] + vbz + i0 * wz0 + i1 * wz1;
      const float gnh = aN[ntl][e] + vbnh;
      const float gni = i0 * wn0 + i1 * wn1 + vbni;
      const float rr = 1.f / (1.f + __expf(-gr));
      const float zz = 1.f / (1.f + __expf(-gz));
      const float xx = rr * gnh + gni;
      const float ex = __expf(2.f * xx);
      const float nn = (ex - 1.f) / (ex + 1.f);
      const float av = b2f(al[bb * 64 + kk]);
      lout[(bb * 64 + kk) * 2 + li] = f2b((1.f - zz) * nn + zz * av);
    }
  }
  __syncthreads();
  const int c0 = wg * 2;
  for (int i = tid; i < BH_; i += 512)
    *(unsigned*)(Hb + (size_t)i * L_ + c0) = *(const unsigned*)&lout[i * 2];
}

// ---------------- workspace map (bytes) — total 43 MB ----------------
#define WS_H     (size_t)0          // bf16 H[b*64+h][l]        4 MB
#define WS_AALT  ((size_t)4 << 20)  // bf16 A[l][b*64+h]        4 MB
#define WS_WHB   ((size_t)8 << 20)  // bf16 Wh[m][l]            2 MB
#define WS_WIB   ((size_t)10 << 20) // bf16 Wi[m][l]            2 MB
#define WS_XB    ((size_t)12 << 20) // bf16 x rows (b,t,f)[l]   1.5 MB
#define WS_WTR   ((size_t)14 << 20) // bf16 WT_r[l][k][h]       8 MB
#define WS_WTZ   ((size_t)22 << 20)
#define WS_WTN   ((size_t)30 << 20)
#define WS_ENCIN ((size_t)38 << 20) // f32 ENCIN[(b,t,f)][m]    3 MB
#define WS_PK    ((size_t)41 << 20) // f32 PK[4][32][1024]      512 KB
#define WS_OUTFC (((size_t)41 << 20) + (512 << 10)) // bf16 OUTFC[b][l]  64 KB
#define WS_BRZ   ((size_t)42 << 20) // f32 [1024][64]           256 KB
#define WS_BZZ   (((size_t)42 << 20) + (256 << 10))
#define WS_BNH   (((size_t)42 << 20) + (512 << 10))
#define WS_BNI   (((size_t)42 << 20) + (768 << 10))

extern "C" void kernel_launch(void* const* d_in, const int* in_sizes, int n_in,
                              void* d_out, int out_size, void* d_ws, size_t ws_size,
                              hipStream_t stream) {
  const float* x   = (const float*)d_in[0];
  const float* Wi  = (const float*)d_in[1];
  const float* Wh  = (const float*)d_in[2];
  const float* Wrh = (const float*)d_in[3];
  const float* brh = (const float*)d_in[4];
  const float* Wri = (const float*)d_in[5];
  const float* bri = (const float*)d_in[6];
  const float* Wzh = (const float*)d_in[7];
  const float* bzh = (const float*)d_in[8];
  const float* Wzi = (const float*)d_in[9];
  const float* bzi = (const float*)d_in[10];
  const float* Wnh = (const float*)d_in[11];
  const float* bnh = (const float*)d_in[12];
  const float* Wni = (const float*)d_in[13];
  const float* bni = (const float*)d_in[14];
  const float* fcw = (const float*)d_in[15];
  const float* fcb = (const float*)d_in[16];
  float* out = (float*)d_out;

  char* ws = (char*)d_ws;
  u16*   Hb    = (u16*)(ws + WS_H);
  u16*   Aalt  = (u16*)(ws + WS_AALT);
  u16*   Whb   = (u16*)(ws + WS_WHB);
  u16*   Wib   = (u16*)(ws + WS_WIB);
  u16*   xb    = (u16*)(ws + WS_XB);
  u16*   WTr   = (u16*)(ws + WS_WTR);
  u16*   WTz   = (u16*)(ws + WS_WTZ);
  u16*   WTn   = (u16*)(ws + WS_WTN);
  float* ENCIN = (float*)(ws + WS_ENCIN);
  float* PK    = (float*)(ws + WS_PK);
  u16*   OUTFC = (u16*)(ws + WS_OUTFC);
  float* BRZ   = (float*)(ws + WS_BRZ);
  float* BZZ   = (float*)(ws + WS_BZZ);
  float* BNH   = (float*)(ws + WS_BNH);
  float* BNI   = (float*)(ws + WS_BNI);

  k_zero<<<1024, 256, 0, stream>>>((uint4*)Hb, 262144);  // h0 = 0 (4 MB)
  k_cvt<<<1024, 256, 0, stream>>>(Wh, Whb, 262144);
  k_cvt<<<1024, 256, 0, stream>>>(Wi, Wib, 262144);
  k_cvt<<<768, 256, 0, stream>>>(x, xb, 196608);
  k_tg<<<1024, 256, 0, stream>>>(Wrh, WTr);
  k_tg<<<1024, 256, 0, stream>>>(Wzh, WTz);
  k_tg<<<1024, 256, 0, stream>>>(Wnh, WTn);
  k_bias<<<1024, 64, 0, stream>>>(brh, bri, bzh, bzi, bnh, bni, BRZ, BZZ, BNH, BNI);
  // all-timestep encoder input attn: ENCIN[(b,t,f)][m] = sum_l x * Wi[m,l]
  k_gemm128<0><<<dim3(8, 12), 256, 0, stream>>>(xb, Wib, ENCIN, 1024, 1024);

  for (int t = 0; t < T_; ++t) {
    // Aalt[m][bh] = sum_l Wh[m,l] * H[bh,l]
    k_gemm128<1><<<dim3(16, 16), 256, 0, stream>>>(Whb, Hb, Aalt, 2048, 1024);
    k_gates<1><<<512, 512, 0, stream>>>(Aalt, WTr, WTz, WTn, BRZ, BZZ, BNH, BNI,
                                        Wri, Wzi, Wni, ENCIN, t, Hb);
  }
  for (int s = 0; s < HOR_; ++s) {
    k_fc<<<256, 256, 0, stream>>>(Hb, fcw, fcb, out, OUTFC, s);
    k_gemm32<<<dim3(8, 4), 256, 0, stream>>>(OUTFC, Wib, PK);
    k_gemm128<1><<<dim3(16, 16), 256, 0, stream>>>(Whb, Hb, Aalt, 2048, 1024);
    k_gates<0><<<512, 512, 0, stream>>>(Aalt, WTr, WTz, WTn, BRZ, BZZ, BNH, BNI,
                                        Wri, Wzi, Wni, PK, 0, Hb);
  }
}

// Round 10
// 996.787 us; speedup vs baseline: 1.4537x; 1.0822x over previous
//
#include <hip/hip_runtime.h>

#define T_ 12
#define L_ 1024
#define H_ 64
#define HOR_ 12
#define BH_ 2048

typedef unsigned short u16;
typedef __attribute__((ext_vector_type(8))) __bf16 bf16x8;
typedef __attribute__((ext_vector_type(8))) u16 u16x8;
typedef __attribute__((ext_vector_type(4))) float f32x4;

__device__ __forceinline__ u16 f2b(float f) {
  union { float f; unsigned u; } v; v.f = f;
  unsigned r = v.u + 0x7FFFu + ((v.u >> 16) & 1u);
  return (u16)(r >> 16);
}
__device__ __forceinline__ float b2f(u16 b) {
  union { unsigned u; float f; } v; v.u = ((unsigned)b) << 16;
  return v.f;
}
__device__ __forceinline__ void gld16(const void* g, void* l) {
  __builtin_amdgcn_global_load_lds((const __attribute__((address_space(1))) void*)g,
                                   (__attribute__((address_space(3))) void*)l, 16, 0, 0);
}

// ---- consolidated fp32 -> bf16 convert: Wh | Wi | x ----
__global__ __launch_bounds__(256) void k_cvt3(const float* __restrict__ Wh,
                                              const float* __restrict__ Wi,
                                              const float* __restrict__ x,
                                              u16* __restrict__ Whb, u16* __restrict__ Wib,
                                              u16* __restrict__ xb) {
  const int bid = blockIdx.x;
  const float* in; u16* out; int i;
  if (bid < 1024)      { in = Wh; out = Whb; i = bid * 256 + threadIdx.x; }
  else if (bid < 2048) { in = Wi; out = Wib; i = (bid - 1024) * 256 + threadIdx.x; }
  else                 { in = x;  out = xb;  i = (bid - 2048) * 256 + threadIdx.x; }
  float4 v = ((const float4*)in)[i];
  ushort4 o;
  o.x = f2b(v.x); o.y = f2b(v.y); o.z = f2b(v.z); o.w = f2b(v.w);
  ((ushort4*)out)[i] = o;
}

// ---- consolidated per-link 64x64 transpose: WT[l][k][h] = W[l][h][k] ----
__global__ __launch_bounds__(256) void k_tg3(const float* __restrict__ Wr,
                                             const float* __restrict__ Wz,
                                             const float* __restrict__ Wn,
                                             u16* __restrict__ WTr, u16* __restrict__ WTz,
                                             u16* __restrict__ WTn) {
  const int sel = blockIdx.x >> 10, l = blockIdx.x & 1023;
  const float* w = (sel == 0 ? Wr : sel == 1 ? Wz : Wn) + (size_t)l * 4096;
  u16* t = (sel == 0 ? WTr : sel == 1 ? WTz : WTn) + (size_t)l * 4096;
  for (int idx = threadIdx.x; idx < 4096; idx += 256) {
    int h = idx >> 6, k = idx & 63;
    t[k * 64 + h] = f2b(w[idx]);
  }
}

// ---- bias pre-transpose+combine: [k][l] scattered -> [l][k] coalesced ----
__global__ __launch_bounds__(64) void k_bias(
    const float* __restrict__ brh, const float* __restrict__ bri,
    const float* __restrict__ bzh, const float* __restrict__ bzi,
    const float* __restrict__ bnh, const float* __restrict__ bni,
    float* __restrict__ BRZ, float* __restrict__ BZZ,
    float* __restrict__ BNH, float* __restrict__ BNI) {
  const int l = blockIdx.x, k = threadIdx.x;
  const int i = k * 1024 + l, o = l * 64 + k;
  BRZ[o] = brh[i] + bri[i];
  BZZ[o] = bzh[i] + bzi[i];
  BNH[o] = bnh[i];
  BNI[o] = bni[i];
}

// -------- 64x128 bf16 NT GEMM: C[M,N] = A[M,K] * B[N,K]^T, fp32 acc --------
template <int OUT_BF16>
__global__ __launch_bounds__(256) void k_gemm128(const u16* __restrict__ A,
                                                 const u16* __restrict__ Bm,
                                                 void* __restrict__ C, int N, int K) {
  __shared__ __align__(16) u16 lA[64 * 32];
  __shared__ __align__(16) u16 lB[128 * 32];
  const int tid = threadIdx.x;
  const int lane = tid & 63, wv = tid >> 6;
  const int m0 = blockIdx.y * 64, n0 = blockIdx.x * 128;
  const int wm = (wv >> 1) * 32, wn = (wv & 1) * 64;
  const int r16 = lane & 15, q4 = lane >> 4;
  f32x4 acc[2][4] = {};
  for (int k0 = 0; k0 < K; k0 += 32) {
    __syncthreads();
    {
      int row = tid >> 2, c = tid & 3;
      gld16(A + (size_t)(m0 + row) * K + k0 + c * 8, lA + tid * 8);
    }
#pragma unroll
    for (int j = 0; j < 2; ++j) {
      int ci = j * 256 + tid;
      int row = ci >> 2, c = ci & 3;
      gld16(Bm + (size_t)(n0 + row) * K + k0 + c * 8, lB + ci * 8);
    }
    __syncthreads();
    bf16x8 af[2], bfv[4];
#pragma unroll
    for (int u = 0; u < 2; ++u)
      af[u] = *(const bf16x8*)&lA[(wm + u * 16 + r16) * 32 + q4 * 8];
#pragma unroll
    for (int u = 0; u < 4; ++u)
      bfv[u] = *(const bf16x8*)&lB[(wn + u * 16 + r16) * 32 + q4 * 8];
#pragma unroll
    for (int i = 0; i < 2; ++i)
#pragma unroll
      for (int j = 0; j < 4; ++j)
        acc[i][j] = __builtin_amdgcn_mfma_f32_16x16x32_bf16(af[i], bfv[j], acc[i][j], 0, 0, 0);
  }
#pragma unroll
  for (int i = 0; i < 2; ++i)
#pragma unroll
    for (int j = 0; j < 4; ++j)
#pragma unroll
      for (int e = 0; e < 4; ++e) {
        size_t row = m0 + wm + i * 16 + q4 * 4 + e;
        size_t col = n0 + wn + j * 16 + r16;
        if (OUT_BF16) ((u16*)C)[row * N + col] = f2b(acc[i][j][e]);
        else          ((float*)C)[row * N + col] = acc[i][j][e];
      }
}

// -------- gates (+fused decoder-input-attn prologue, +fused fc epilogue) --------
// 4 waves/link (M-half x N-half), 2 links/block, 512 blocks.
// ENC: encoder (inp=ENCIN) vs decoder (DECIN computed in-block from OUTFC x Wib)
// Z:   attn'd hidden is identically zero (t=0) -> skip Aalt loads/MFMA
// FC:  epilogue computes out[b,s_out,l] + OUTFC_w from the new hidden in LDS
template <int ENC, int Z, int FC>
__global__ __launch_bounds__(512, 4) void k_gates(
    const u16* __restrict__ Aalt, const u16* __restrict__ WTr, const u16* __restrict__ WTz,
    const u16* __restrict__ WTn, const float* __restrict__ BRZ, const float* __restrict__ BZZ,
    const float* __restrict__ BNH, const float* __restrict__ BNI,
    const float* __restrict__ Wir, const float* __restrict__ Wiz, const float* __restrict__ Win,
    const float* __restrict__ inp, const u16* __restrict__ OUTFC_r, const u16* __restrict__ Wib,
    const float* __restrict__ fcw, const float* __restrict__ fcb,
    float* __restrict__ outp, u16* __restrict__ OUTFC_w, int t, int s_out,
    u16* __restrict__ Hb) {
  __shared__ __align__(8) u16 lout[BH_ * 2];
  __shared__ __align__(16) u16 lWi[2048];
  __shared__ float di0[2][32];
  const int tid = threadIdx.x;
  const int lane = tid & 63, wv = tid >> 6;
  const int li = wv >> 2, mh = (wv >> 1) & 1, nh = wv & 1;
  const int bid = blockIdx.x;
  const int wg = (bid & 7) * 64 + (bid >> 3);   // chunked XCD map
  const int l = wg * 2 + li;
  const int r16 = lane & 15, q4 = lane >> 4;

  if (ENC == 0) {       // ---- decoder input-attn prologue: DECIN for our 2 columns ----
    if (tid < 256) ((uint4*)lWi)[tid] = ((const uint4*)(Wib + (size_t)(wg * 2) * 1024))[tid];
    __syncthreads();
    const int pair = tid >> 3, sub = tid & 7;
    const int pb = pair >> 1, pl = pair & 1;
    const u16* orow = OUTFC_r + pb * 1024 + sub * 128;
    const u16* wrow = lWi + pl * 1024 + sub * 128;
    float s = 0.f;
#pragma unroll
    for (int j = 0; j < 16; ++j) {
      u16x8 o = *(const u16x8*)(orow + j * 8);
      u16x8 w = *(const u16x8*)(wrow + j * 8);
#pragma unroll
      for (int e = 0; e < 8; ++e) s += b2f(o[e]) * b2f(w[e]);
    }
    s += __shfl_xor(s, 1); s += __shfl_xor(s, 2); s += __shfl_xor(s, 4);
    if (sub == 0) di0[pl][pb] = s;
    __syncthreads();
  }

  const u16* al = Aalt + (size_t)l * BH_;
  bf16x8 a[2];
  f32x4 aR[2] = {}, aZ[2] = {}, aN[2] = {};
  if (Z == 0) {
#pragma unroll
    for (int kt = 0; kt < 2; ++kt)
      a[kt] = *(const bf16x8*)&al[(mh * 16 + r16) * 64 + kt * 32 + q4 * 8];
    const size_t wbase = (size_t)l * 4096 + (size_t)(nh * 32 + r16) * 64 + q4 * 8;
#define DO_GATE(W, acc)                                                              \
    {                                                                                \
      bf16x8 w00 = *(const bf16x8*)&W[wbase];                                        \
      bf16x8 w01 = *(const bf16x8*)&W[wbase + 32];                                   \
      bf16x8 w10 = *(const bf16x8*)&W[wbase + 1024];                                 \
      bf16x8 w11 = *(const bf16x8*)&W[wbase + 1024 + 32];                            \
      acc[0] = __builtin_amdgcn_mfma_f32_16x16x32_bf16(a[0], w00, acc[0], 0, 0, 0);  \
      acc[0] = __builtin_amdgcn_mfma_f32_16x16x32_bf16(a[1], w01, acc[0], 0, 0, 0);  \
      acc[1] = __builtin_amdgcn_mfma_f32_16x16x32_bf16(a[0], w10, acc[1], 0, 0, 0);  \
      acc[1] = __builtin_amdgcn_mfma_f32_16x16x32_bf16(a[1], w11, acc[1], 0, 0, 0);  \
    }
    DO_GATE(WTr, aR)
    DO_GATE(WTz, aZ)
    DO_GATE(WTn, aN)
#undef DO_GATE
  }

  float i0v[4], i1v[4];
#pragma unroll
  for (int e = 0; e < 4; ++e) {
    const int bb = mh * 16 + q4 * 4 + e;
    if (ENC) {
      i0v[e] = inp[(((size_t)bb * T_ + t) * 2 + 0) * L_ + l];
      i1v[e] = inp[(((size_t)bb * T_ + t) * 2 + 1) * L_ + l];
    } else {
      i0v[e] = di0[li][bb];
      i1v[e] = 0.f;
    }
  }
#pragma unroll
  for (int ntl = 0; ntl < 2; ++ntl) {
    const int kk = nh * 32 + ntl * 16 + r16;
    const float vbr  = BRZ[l * 64 + kk];
    const float vbz  = BZZ[l * 64 + kk];
    const float vbnh = BNH[l * 64 + kk];
    const float vbni = BNI[l * 64 + kk];
    const float wr0 = Wir[l * 128 + kk], wr1 = Wir[l * 128 + 64 + kk];
    const float wz0 = Wiz[l * 128 + kk], wz1 = Wiz[l * 128 + 64 + kk];
    const float wn0 = Win[l * 128 + kk], wn1 = Win[l * 128 + 64 + kk];
#pragma unroll
    for (int e = 0; e < 4; ++e) {
      const int bb = mh * 16 + q4 * 4 + e;
      const float i0 = i0v[e], i1 = i1v[e];
      const float gr = aR[ntl][e] + vbr + i0 * wr0 + i1 * wr1;
      const float gz = aZ[ntl][e] + vbz + i0 * wz0 + i1 * wz1;
      const float gnh = aN[ntl][e] + vbnh;
      const float gni = i0 * wn0 + i1 * wn1 + vbni;
      const float rr = 1.f / (1.f + __expf(-gr));
      const float zz = 1.f / (1.f + __expf(-gz));
      const float xx = rr * gnh + gni;
      const float ex = __expf(2.f * xx);
      const float nn = (ex - 1.f) / (ex + 1.f);
      const float av = Z ? 0.f : b2f(al[bb * 64 + kk]);
      lout[(bb * 64 + kk) * 2 + li] = f2b((1.f - zz) * nn + zz * av);
    }
  }
  __syncthreads();
  const int c0 = wg * 2;
  for (int i = tid; i < BH_; i += 512)
    *(unsigned*)(Hb + (size_t)i * L_ + c0) = *(const unsigned*)&lout[i * 2];

  if (FC) {            // ---- fc epilogue: out[b,s_out,l] from new hidden in lout ----
    if (tid < 64) {
      const int b = tid & 31, li2 = tid >> 5;
      const int lf = wg * 2 + li2;
      float acc = fcb[lf];
      const float* wp = fcw + (size_t)lf * 64;
#pragma unroll 8
      for (int h = 0; h < 64; ++h) acc += b2f(lout[(b * 64 + h) * 2 + li2]) * wp[h];
      outp[((size_t)b * HOR_ + s_out) * L_ + lf] = acc;
      OUTFC_w[(size_t)b * 1024 + lf] = f2b(acc);
    }
  }
}

// ---------------- workspace map (bytes) — total ~43 MB ----------------
#define WS_H     (size_t)0          // bf16 H[b*64+h][l]        4 MB
#define WS_AALT  ((size_t)4 << 20)  // bf16 A[l][b*64+h]        4 MB
#define WS_WHB   ((size_t)8 << 20)  // bf16 Wh[m][l]            2 MB
#define WS_WIB   ((size_t)10 << 20) // bf16 Wi[m][l]            2 MB
#define WS_XB    ((size_t)12 << 20) // bf16 x rows (b,t,f)[l]   1.5 MB
#define WS_WTR   ((size_t)14 << 20) // bf16 WT_r[l][k][h]       8 MB
#define WS_WTZ   ((size_t)22 << 20)
#define WS_WTN   ((size_t)30 << 20)
#define WS_ENCIN ((size_t)38 << 20) // f32 ENCIN[(b,t,f)][m]    3 MB
#define WS_OFC0  ((size_t)41 << 20) // bf16 OUTFC ping          64 KB
#define WS_OFC1  (((size_t)41 << 20) + (64 << 10))  // bf16 OUTFC pong
#define WS_BRZ   ((size_t)42 << 20) // f32 [1024][64]           256 KB
#define WS_BZZ   (((size_t)42 << 20) + (256 << 10))
#define WS_BNH   (((size_t)42 << 20) + (512 << 10))
#define WS_BNI   (((size_t)42 << 20) + (768 << 10))

extern "C" void kernel_launch(void* const* d_in, const int* in_sizes, int n_in,
                              void* d_out, int out_size, void* d_ws, size_t ws_size,
                              hipStream_t stream) {
  const float* x   = (const float*)d_in[0];
  const float* Wi  = (const float*)d_in[1];
  const float* Wh  = (const float*)d_in[2];
  const float* Wrh = (const float*)d_in[3];
  const float* brh = (const float*)d_in[4];
  const float* Wri = (const float*)d_in[5];
  const float* bri = (const float*)d_in[6];
  const float* Wzh = (const float*)d_in[7];
  const float* bzh = (const float*)d_in[8];
  const float* Wzi = (const float*)d_in[9];
  const float* bzi = (const float*)d_in[10];
  const float* Wnh = (const float*)d_in[11];
  const float* bnh = (const float*)d_in[12];
  const float* Wni = (const float*)d_in[13];
  const float* bni = (const float*)d_in[14];
  const float* fcw = (const float*)d_in[15];
  const float* fcb = (const float*)d_in[16];
  float* out = (float*)d_out;

  char* ws = (char*)d_ws;
  u16*   Hb    = (u16*)(ws + WS_H);
  u16*   Aalt  = (u16*)(ws + WS_AALT);
  u16*   Whb   = (u16*)(ws + WS_WHB);
  u16*   Wib   = (u16*)(ws + WS_WIB);
  u16*   xb    = (u16*)(ws + WS_XB);
  u16*   WTr   = (u16*)(ws + WS_WTR);
  u16*   WTz   = (u16*)(ws + WS_WTZ);
  u16*   WTn   = (u16*)(ws + WS_WTN);
  float* ENCIN = (float*)(ws + WS_ENCIN);
  u16*   OFC0  = (u16*)(ws + WS_OFC0);
  u16*   OFC1  = (u16*)(ws + WS_OFC1);
  float* BRZ   = (float*)(ws + WS_BRZ);
  float* BZZ   = (float*)(ws + WS_BZZ);
  float* BNH   = (float*)(ws + WS_BNH);
  float* BNI   = (float*)(ws + WS_BNI);

  k_cvt3<<<2816, 256, 0, stream>>>(Wh, Wi, x, Whb, Wib, xb);
  k_tg3<<<3072, 256, 0, stream>>>(Wrh, Wzh, Wnh, WTr, WTz, WTn);
  k_bias<<<1024, 64, 0, stream>>>(brh, bri, bzh, bzi, bnh, bni, BRZ, BZZ, BNH, BNI);
  // all-timestep encoder input attn: ENCIN[(b,t,f)][m] = sum_l x * Wi[m,l]
  k_gemm128<0><<<dim3(8, 12), 256, 0, stream>>>(xb, Wib, ENCIN, 1024, 1024);

  // encoder: t=0 has H=0 -> skip hidden-attn GEMM, Z-path gates
  k_gates<1, 1, 0><<<512, 512, 0, stream>>>(Aalt, WTr, WTz, WTn, BRZ, BZZ, BNH, BNI,
                                            Wri, Wzi, Wni, ENCIN, OFC0, Wib, fcw, fcb,
                                            out, OFC0, 0, 0, Hb);
  for (int t = 1; t < T_; ++t) {
    k_gemm128<1><<<dim3(16, 16), 256, 0, stream>>>(Whb, Hb, Aalt, 2048, 1024);
    if (t < T_ - 1)
      k_gates<1, 0, 0><<<512, 512, 0, stream>>>(Aalt, WTr, WTz, WTn, BRZ, BZZ, BNH, BNI,
                                                Wri, Wzi, Wni, ENCIN, OFC0, Wib, fcw, fcb,
                                                out, OFC0, t, 0, Hb);
    else  // t=11: fc epilogue -> out slot 0 + OUTFC ping
      k_gates<1, 0, 1><<<512, 512, 0, stream>>>(Aalt, WTr, WTz, WTn, BRZ, BZZ, BNH, BNI,
                                                Wri, Wzi, Wni, ENCIN, OFC0, Wib, fcw, fcb,
                                                out, OFC0, t, 0, Hb);
  }
  // decoder: s = 0..10 (step 11's hidden update is unused)
  for (int s = 0; s <= 10; ++s) {
    const u16* ofr = (s & 1) ? OFC1 : OFC0;
    u16*       ofw = (s & 1) ? OFC0 : OFC1;
    k_gemm128<1><<<dim3(16, 16), 256, 0, stream>>>(Whb, Hb, Aalt, 2048, 1024);
    k_gates<0, 0, 1><<<512, 512, 0, stream>>>(Aalt, WTr, WTz, WTn, BRZ, BZZ, BNH, BNI,
                                              Wri, Wzi, Wni, ENCIN, ofr, Wib, fcw, fcb,
                                              out, ofw, 0, s + 1, Hb);
  }
}